// Round 1
// baseline (277.048 us; speedup 1.0000x reference)
//
#include <hip/hip_runtime.h>
#include <hip/hip_bf16.h>
#include <stdint.h>

// Problem dims (fixed)
#define BATCH 2
#define SEQ   2048
#define HID   1024
#define NHEAD 16
#define HD    64
#define MROWS (BATCH*SEQ)   // 4096

typedef __attribute__((ext_vector_type(8))) short bf16x8;
typedef __attribute__((ext_vector_type(4))) float f32x4;

// ---- helpers ----------------------------------------------------------
__device__ inline unsigned short f2bf(float f){
  union { float f; unsigned u; } v; v.f = f;
  unsigned r = v.u + 0x7fffu + ((v.u >> 16) & 1u);   // RNE
  return (unsigned short)(r >> 16);
}
__device__ inline unsigned packbf(float a, float b){
  return (unsigned)f2bf(a) | ((unsigned)f2bf(b) << 16);
}
__device__ inline void lds_load16(const short* g, short* l){
  // async global->LDS, 16B per lane; LDS dest = wave-uniform base + lane*16
  __builtin_amdgcn_global_load_lds(
      (const __attribute__((address_space(1))) void*)g,
      (__attribute__((address_space(3))) void*)l, 16, 0, 0);
}

// ---- cast kernels -----------------------------------------------------
// xb = bf16(x + pos), xv = bf16(x). 4 elems/thread via float4.
__global__ __launch_bounds__(256) void cast_xpos(
    const float* __restrict__ x, const float* __restrict__ pos,
    short* __restrict__ xb, short* __restrict__ xv){
  int i = blockIdx.x * 256 + threadIdx.x;           // 0 .. 1M-1 (float4 units)
  float4 xa = ((const float4*)x)[i];
  float4 pa = ((const float4*)pos)[i & (SEQ*HID/4 - 1)];
  short4 sb, sv;
  sb.x = (short)f2bf(xa.x + pa.x); sb.y = (short)f2bf(xa.y + pa.y);
  sb.z = (short)f2bf(xa.z + pa.z); sb.w = (short)f2bf(xa.w + pa.w);
  sv.x = (short)f2bf(xa.x); sv.y = (short)f2bf(xa.y);
  sv.z = (short)f2bf(xa.z); sv.w = (short)f2bf(xa.w);
  ((short4*)xb)[i] = sb;
  ((short4*)xv)[i] = sv;
}

__global__ __launch_bounds__(256) void cast_wmat(
    const float* __restrict__ in, short* __restrict__ out){
  int i = blockIdx.x * 256 + threadIdx.x;
  float4 a = ((const float4*)in)[i];
  short4 s;
  s.x = (short)f2bf(a.x); s.y = (short)f2bf(a.y);
  s.z = (short)f2bf(a.z); s.w = (short)f2bf(a.w);
  ((short4*)out)[i] = s;
}

// ---- GEMM: C[M,N] = A[M,K] * W[N,K]^T, bf16 inputs --------------------
// 128x128 tile, BK=32, 256 threads (4 waves, 2x2), each wave 64x64.
// A-operand selected per column-block (xb for Q/K cols, xv for V cols).
template<bool F32OUT>
__global__ __launch_bounds__(256) void gemm_bt(
    const short* __restrict__ A0, const short* __restrict__ A1, int split_bx,
    const short* __restrict__ W, void* __restrict__ Cout, int K, int ldc){
  __shared__ alignas(16) short As[128*32];
  __shared__ alignas(16) short Bs[128*32];
  const int bx = blockIdx.x, by = blockIdx.y;
  const short* A = (bx < split_bx) ? A0 : A1;
  const int tid  = threadIdx.x;
  const int w    = tid >> 6, lane = tid & 63;
  const int g    = lane >> 4, c = lane & 15;
  const int wr   = w >> 1, wc = w & 1;

  f32x4 acc[4][4];
#pragma unroll
  for (int m = 0; m < 4; ++m)
#pragma unroll
    for (int n = 0; n < 4; ++n) acc[m][n] = (f32x4){0.f, 0.f, 0.f, 0.f};

  const short* Abase = A + (size_t)(by*128) * K;
  const short* Wbase = W + (size_t)(bx*128) * K;

  for (int kt = 0; kt < K; kt += 32){
    // stage A-tile and B-tile: 512 16B-chunks each, 2 per lane per tile.
    // chunk ci -> row = ci>>2, sub = ci&3 (32 elems/row = 4 chunks)
#pragma unroll
    for (int j = 0; j < 2; ++j){
      int ci  = w*128 + j*64 + lane;
      int row = ci >> 2, sub = ci & 3;
      lds_load16(Abase + (size_t)row*K + kt + sub*8, &As[(w*128 + j*64)*8]);
      lds_load16(Wbase + (size_t)row*K + kt + sub*8, &Bs[(w*128 + j*64)*8]);
    }
    __syncthreads();   // drains vmcnt -> staged data visible

    bf16x8 af[4], bfr[4];
#pragma unroll
    for (int m = 0; m < 4; ++m)
      af[m] = *(const bf16x8*)&As[(wr*64 + m*16 + c)*32 + g*8];
#pragma unroll
    for (int n = 0; n < 4; ++n)
      bfr[n] = *(const bf16x8*)&Bs[(wc*64 + n*16 + c)*32 + g*8];
#pragma unroll
    for (int m = 0; m < 4; ++m)
#pragma unroll
      for (int n = 0; n < 4; ++n)
        acc[m][n] = __builtin_amdgcn_mfma_f32_16x16x32_bf16(af[m], bfr[n], acc[m][n], 0, 0, 0);
    __syncthreads();   // protect LDS before next stage
  }

  // C/D frag: col = lane&15, row = (lane>>4)*4 + reg
  const int row0 = by*128 + wr*64;
  const int col0 = bx*128 + wc*64;
#pragma unroll
  for (int m = 0; m < 4; ++m)
#pragma unroll
    for (int n = 0; n < 4; ++n)
#pragma unroll
      for (int r = 0; r < 4; ++r){
        size_t idx = (size_t)(row0 + m*16 + g*4 + r) * ldc + (col0 + n*16 + c);
        if constexpr (F32OUT) ((float*)Cout)[idx] = acc[m][n][r];
        else                  ((short*)Cout)[idx] = (short)f2bf(acc[m][n][r]);
      }
}

// ---- flash attention (causal) -----------------------------------------
// qkv: [B*SEQ, 3*HID] bf16 rows (Q cols 0..1023, K 1024..2047, V 2048..3071)
// out: [B*SEQ, HID] bf16 (head-major within row)
// Block: 4 waves; wave w owns q-rows [qt*64 + w*16, +16). KV chunk = 32.
// Swapped QK^T: S^T = mfma(K_frag, Q_frag) -> lane owns q = lane&15.
// Swapped PV:   O^T = mfma(V^T_frag, P^T_frag) -> q stays lane-local.
__global__ __launch_bounds__(256) void attn_fwd(
    const short* __restrict__ qkv, short* __restrict__ out){
  const int qt  = gridDim.x - 1 - blockIdx.x;   // heavy (late-diagonal) blocks first
  const int bh  = blockIdx.y;
  const int b   = bh >> 4, h = bh & 15;
  const int tid = threadIdx.x;
  const int w   = tid >> 6, lane = tid & 63;
  const int g   = lane >> 4, c = lane & 15;

  __shared__ alignas(16) short Vt[64*40];       // V^T tile: [d][kv], stride 40 (pad)
  __shared__ alignas(16) short Pl[4*16*40];     // per-wave P: [q][kv], stride 40

  const int q0 = qt*64 + w*16;
  const size_t rowb = (size_t)b * SEQ;

  // Q fragments (B-operand): lane holds Q[q0+c][dchunk*32 + g*8 .. +7]
  const short* qptr = qkv + (rowb + q0 + c)*3072 + h*HD;
  bf16x8 qf0 = *(const bf16x8*)(qptr + g*8);
  bf16x8 qf1 = *(const bf16x8*)(qptr + 32 + g*8);

  const short* kbase = qkv + rowb*3072 + HID   + h*HD;
  const short* vbase = qkv + rowb*3072 + 2*HID + h*HD;

  f32x4 ot[4];
#pragma unroll
  for (int dt = 0; dt < 4; ++dt) ot[dt] = (f32x4){0.f, 0.f, 0.f, 0.f};
  float mrow = -1e30f, lrow = 0.f;
  const int qg = q0 + c;

  const int skv = tid >> 3;          // staging: kv row 0..31
  const int sd0 = (tid & 7) * 8;     // staging: d offset
  const int nch = (qt + 1) * 2;      // 32-wide chunks up to block diagonal

  for (int ch = 0; ch < nch; ++ch){
    const int c0 = ch * 32;
    __syncthreads();                 // Vt free (prev PV done)

    // stage V^T: read V[c0+skv][sd0..+7], scatter-transpose into LDS
    bf16x8 v8 = *(const bf16x8*)(vbase + (size_t)(c0 + skv)*3072 + sd0);
    // K fragments (A-operand) direct from global (L2-resident)
    bf16x8 kf00 = *(const bf16x8*)(kbase + (size_t)(c0      + c)*3072 + g*8);
    bf16x8 kf01 = *(const bf16x8*)(kbase + (size_t)(c0      + c)*3072 + 32 + g*8);
    bf16x8 kf10 = *(const bf16x8*)(kbase + (size_t)(c0 + 16 + c)*3072 + g*8);
    bf16x8 kf11 = *(const bf16x8*)(kbase + (size_t)(c0 + 16 + c)*3072 + 32 + g*8);
#pragma unroll
    for (int j = 0; j < 8; ++j) Vt[(sd0 + j)*40 + skv] = v8[j];
    __syncthreads();                 // Vt ready

    // S^T tiles: rows = keys (2 tiles of 16), cols = q (lane&15)
    f32x4 z = (f32x4){0.f, 0.f, 0.f, 0.f};
    f32x4 s0 = __builtin_amdgcn_mfma_f32_16x16x32_bf16(kf00, qf0, z, 0, 0, 0);
    s0       = __builtin_amdgcn_mfma_f32_16x16x32_bf16(kf01, qf1, s0, 0, 0, 0);
    f32x4 s1 = __builtin_amdgcn_mfma_f32_16x16x32_bf16(kf10, qf0, z, 0, 0, 0);
    s1       = __builtin_amdgcn_mfma_f32_16x16x32_bf16(kf11, qf1, s1, 0, 0, 0);

    // scale + causal mask (lane's elem: key = c0 + t*16 + g*4 + r, q = qg)
    float sv[8];
#pragma unroll
    for (int r = 0; r < 4; ++r){
      int k0i = c0 + g*4 + r;
      int k1i = c0 + 16 + g*4 + r;
      sv[r]     = (k0i > qg) ? -1e30f : s0[r]*0.125f;
      sv[4 + r] = (k1i > qg) ? -1e30f : s1[r]*0.125f;
    }
    // online softmax: row spread over 4 lanes (xor 16, 32)
    float cm = sv[0];
#pragma unroll
    for (int i = 1; i < 8; ++i) cm = fmaxf(cm, sv[i]);
    cm = fmaxf(cm, __shfl_xor(cm, 16));
    cm = fmaxf(cm, __shfl_xor(cm, 32));
    float mnew  = fmaxf(mrow, cm);
    float alpha = __expf(mrow - mnew);
    float pv[8];
    float ps = 0.f;
#pragma unroll
    for (int i = 0; i < 8; ++i){ pv[i] = __expf(sv[i] - mnew); ps += pv[i]; }
    ps += __shfl_xor(ps, 16);
    ps += __shfl_xor(ps, 32);
    lrow = lrow * alpha + ps;
    mrow = mnew;
#pragma unroll
    for (int dt = 0; dt < 4; ++dt)
#pragma unroll
      for (int r = 0; r < 4; ++r) ot[dt][r] *= alpha;

    // P -> LDS (bf16), re-fragment for PV B-operand
    short* pwbase = &Pl[w*640 + c*40];
    ((unsigned*)(pwbase + g*4))[0]      = packbf(pv[0], pv[1]);
    ((unsigned*)(pwbase + g*4))[1]      = packbf(pv[2], pv[3]);
    ((unsigned*)(pwbase + 16 + g*4))[0] = packbf(pv[4], pv[5]);
    ((unsigned*)(pwbase + 16 + g*4))[1] = packbf(pv[6], pv[7]);
    asm volatile("s_waitcnt lgkmcnt(0)" ::: "memory");

    // PV: O^T[d][q] += V^T[d][kv] * P^T[kv][q]
    bf16x8 pb = *(const bf16x8*)(pwbase + g*8);   // P[q=c][kv=g*8..+7]
#pragma unroll
    for (int dt = 0; dt < 4; ++dt){
      bf16x8 va = *(const bf16x8*)&Vt[(dt*16 + c)*40 + g*8];
      ot[dt] = __builtin_amdgcn_mfma_f32_16x16x32_bf16(va, pb, ot[dt], 0, 0, 0);
    }
  }

  // epilogue: O^T frag -> out[b, q, h*64 + d], normalize by lrow
  float inv = 1.f / lrow;
  short* obase = out + (rowb + q0 + c)*HID + h*HD;
#pragma unroll
  for (int dt = 0; dt < 4; ++dt)
#pragma unroll
    for (int r = 0; r < 4; ++r)
      obase[dt*16 + g*4 + r] = (short)f2bf(ot[dt][r] * inv);
}

// ---- launch -----------------------------------------------------------
extern "C" void kernel_launch(void* const* d_in, const int* in_sizes, int n_in,
                              void* d_out, int out_size, void* d_ws, size_t ws_size,
                              hipStream_t stream){
  const float* x    = (const float*)d_in[0];
  const float* pos  = (const float*)d_in[1];
  const float* Wqkv = (const float*)d_in[2];
  const float* Wout = (const float*)d_in[3];

  // workspace layout (shorts): 48 MB total
  short* xb     = (short*)d_ws;                 // [4096,1024] bf16(x+pos)
  short* xv     = xb    + (size_t)MROWS*HID;    // [4096,1024] bf16(x)
  short* wqkvb  = xv    + (size_t)MROWS*HID;    // [3072,1024]
  short* woutb  = wqkvb + (size_t)3*HID*HID;    // [1024,1024]
  short* qkv    = woutb + (size_t)HID*HID;      // [4096,3072]
  short* attn_o = xb;                           // reuse xb (dead after QKV gemm)

  cast_xpos<<<dim3(MROWS*HID/1024), 256, 0, stream>>>(x, pos, xb, xv);
  cast_wmat<<<dim3(3*HID*HID/1024), 256, 0, stream>>>(Wqkv, wqkvb);
  cast_wmat<<<dim3(HID*HID/1024),   256, 0, stream>>>(Wout, woutb);

  // merged QKV projection: cols [0,2048) use xb (x+pos), cols [2048,3072) use xv
  gemm_bt<false><<<dim3(24, 32), 256, 0, stream>>>(xb, xv, 16, wqkvb, qkv, HID, 3*HID);

  attn_fwd<<<dim3(32, 32), 256, 0, stream>>>(qkv, attn_o);

  gemm_bt<true><<<dim3(8, 32), 256, 0, stream>>>(attn_o, attn_o, 8, woutb, d_out, HID, HID);
}

// Round 2
// 243.268 us; speedup vs baseline: 1.1389x; 1.1389x over previous
//
#include <hip/hip_runtime.h>
#include <hip/hip_bf16.h>
#include <stdint.h>

// Problem dims (fixed)
#define BATCH 2
#define SEQ   2048
#define HID   1024
#define NHEAD 16
#define HD    64
#define MROWS (BATCH*SEQ)   // 4096

typedef __attribute__((ext_vector_type(8))) short bf16x8;
typedef __attribute__((ext_vector_type(4))) float f32x4;

// ---- helpers ----------------------------------------------------------
__device__ inline unsigned short f2bf(float f){
  union { float f; unsigned u; } v; v.f = f;
  unsigned r = v.u + 0x7fffu + ((v.u >> 16) & 1u);   // RNE
  return (unsigned short)(r >> 16);
}
__device__ inline unsigned packbf(float a, float b){
  return (unsigned)f2bf(a) | ((unsigned)f2bf(b) << 16);
}
__device__ inline void lds_load16(const short* g, short* l){
  // async global->LDS, 16B per lane; LDS dest = wave-uniform base + lane*16
  __builtin_amdgcn_global_load_lds(
      (const __attribute__((address_space(1))) void*)g,
      (__attribute__((address_space(3))) void*)l, 16, 0, 0);
}

// ---- cast kernels -----------------------------------------------------
__global__ __launch_bounds__(256) void cast_xpos(
    const float* __restrict__ x, const float* __restrict__ pos,
    short* __restrict__ xb, short* __restrict__ xv){
  int i = blockIdx.x * 256 + threadIdx.x;
  float4 xa = ((const float4*)x)[i];
  float4 pa = ((const float4*)pos)[i & (SEQ*HID/4 - 1)];
  short4 sb, sv;
  sb.x = (short)f2bf(xa.x + pa.x); sb.y = (short)f2bf(xa.y + pa.y);
  sb.z = (short)f2bf(xa.z + pa.z); sb.w = (short)f2bf(xa.w + pa.w);
  sv.x = (short)f2bf(xa.x); sv.y = (short)f2bf(xa.y);
  sv.z = (short)f2bf(xa.z); sv.w = (short)f2bf(xa.w);
  ((short4*)xb)[i] = sb;
  ((short4*)xv)[i] = sv;
}

__global__ __launch_bounds__(256) void cast_wmat(
    const float* __restrict__ in, short* __restrict__ out){
  int i = blockIdx.x * 256 + threadIdx.x;
  float4 a = ((const float4*)in)[i];
  short4 s;
  s.x = (short)f2bf(a.x); s.y = (short)f2bf(a.y);
  s.z = (short)f2bf(a.z); s.w = (short)f2bf(a.w);
  ((short4*)out)[i] = s;
}

// ---- GEMM: C[M,N] = A[M,K] * W[N,K]^T, bf16 inputs --------------------
// 128x128 tile, BK=32, 256 threads (4 waves, 2x2), each wave 64x64.
template<bool F32OUT>
__global__ __launch_bounds__(256) void gemm_bt(
    const short* __restrict__ A0, const short* __restrict__ A1, int split_bx,
    const short* __restrict__ W, void* __restrict__ Cout, int K, int ldc){
  __shared__ alignas(16) short As[128*32];
  __shared__ alignas(16) short Bs[128*32];
  const int bx = blockIdx.x, by = blockIdx.y;
  const short* A = (bx < split_bx) ? A0 : A1;
  const int tid  = threadIdx.x;
  const int w    = tid >> 6, lane = tid & 63;
  const int g    = lane >> 4, c = lane & 15;
  const int wr   = w >> 1, wc = w & 1;

  f32x4 acc[4][4];
#pragma unroll
  for (int m = 0; m < 4; ++m)
#pragma unroll
    for (int n = 0; n < 4; ++n) acc[m][n] = (f32x4){0.f, 0.f, 0.f, 0.f};

  const short* Abase = A + (size_t)(by*128) * K;
  const short* Wbase = W + (size_t)(bx*128) * K;

  for (int kt = 0; kt < K; kt += 32){
#pragma unroll
    for (int j = 0; j < 2; ++j){
      int ci  = w*128 + j*64 + lane;
      int row = ci >> 2, sub = ci & 3;
      lds_load16(Abase + (size_t)row*K + kt + sub*8, &As[(w*128 + j*64)*8]);
      lds_load16(Wbase + (size_t)row*K + kt + sub*8, &Bs[(w*128 + j*64)*8]);
    }
    __syncthreads();

    bf16x8 af[4], bfr[4];
#pragma unroll
    for (int m = 0; m < 4; ++m)
      af[m] = *(const bf16x8*)&As[(wr*64 + m*16 + c)*32 + g*8];
#pragma unroll
    for (int n = 0; n < 4; ++n)
      bfr[n] = *(const bf16x8*)&Bs[(wc*64 + n*16 + c)*32 + g*8];
#pragma unroll
    for (int m = 0; m < 4; ++m)
#pragma unroll
      for (int n = 0; n < 4; ++n)
        acc[m][n] = __builtin_amdgcn_mfma_f32_16x16x32_bf16(af[m], bfr[n], acc[m][n], 0, 0, 0);
    __syncthreads();
  }

  const int row0 = by*128 + wr*64;
  const int col0 = bx*128 + wc*64;
#pragma unroll
  for (int m = 0; m < 4; ++m)
#pragma unroll
    for (int n = 0; n < 4; ++n)
#pragma unroll
      for (int r = 0; r < 4; ++r){
        size_t idx = (size_t)(row0 + m*16 + g*4 + r) * ldc + (col0 + n*16 + c);
        if constexpr (F32OUT) ((float*)Cout)[idx] = acc[m][n][r];
        else                  ((short*)Cout)[idx] = (short)f2bf(acc[m][n][r]);
      }
}

// ---- flash attention (causal), KVBLK=64, shared K/V LDS tiles ---------
// Block: 4 waves; wave w owns q-rows [qt*64 + w*16, +16).
// K staged into LDS[64][64] via global_load_lds, XOR-swizzled on the
// global-source side (chunk c -> c ^ (row&7)); reads apply the same XOR.
// V staged transposed (Vt[d][kv]) via reg->scatter, swizzled the same way;
// scatter assignment (lane=kv, wave=d-block) covers all 32 banks/instr.
// Swapped QK^T: S^T = mfma(K, Q) -> lane owns q = lane&15.
// Swapped PV:   O^T = mfma(V^T, P^T) -> q stays lane-local.
__global__ __launch_bounds__(256) void attn_fwd(
    const short* __restrict__ qkv, short* __restrict__ out){
  const int qt  = gridDim.x - 1 - blockIdx.x;   // heavy blocks first
  const int bh  = blockIdx.y;
  const int b   = bh >> 4, h = bh & 15;
  const int tid = threadIdx.x;
  const int w   = tid >> 6, lane = tid & 63;
  const int g   = lane >> 4, c = lane & 15;

  __shared__ alignas(16) short Ks[64*64];       // K[kv][d], swizzled chunks
  __shared__ alignas(16) short Vt[64*64];       // V^T[d][kv], swizzled chunks
  __shared__ alignas(16) short Pl[4*16*72];     // per-wave P[q][kv], pad 72

  const int q0 = qt*64 + w*16;
  const size_t rowb = (size_t)b * SEQ;

  // Q fragments (B-operand): lane holds Q[q0+c][dh*32 + g*8 .. +7]
  const short* qptr = qkv + (rowb + q0 + c)*3072 + h*HD;
  bf16x8 qf0 = *(const bf16x8*)(qptr + g*8);
  bf16x8 qf1 = *(const bf16x8*)(qptr + 32 + g*8);

  const short* kbase = qkv + rowb*3072 + HID   + h*HD;
  const short* vbase = qkv + rowb*3072 + 2*HID + h*HD;

  f32x4 ot[4];
#pragma unroll
  for (int dt = 0; dt < 4; ++dt) ot[dt] = (f32x4){0.f, 0.f, 0.f, 0.f};
  float mrow = -1e30f, lrow = 0.f;
  const int qg = q0 + c;
  short* pw = &Pl[w*16*72];

  const int nch = qt + 1;                       // 64-wide chunks to diagonal
  for (int ch = 0; ch < nch; ++ch){
    const int c0 = ch * 64;
    __syncthreads();                            // K/V tiles free

    // stage K: 512 16B-chunks, 2 per thread; source pre-swizzled
#pragma unroll
    for (int j = 0; j < 2; ++j){
      int pc  = w*128 + j*64 + lane;            // physical chunk in LDS
      int row = pc >> 3;
      int lc  = (pc & 7) ^ (row & 7);           // logical (global) chunk
      lds_load16(kbase + (size_t)(c0 + row)*3072 + lc*8, &Ks[(w*128 + j*64)*8]);
    }
    // stage V^T: lane reads V[c0+lane][w*16 .. +15], scatters swizzled
    {
      const short* vp = vbase + (size_t)(c0 + lane)*3072 + w*16;
      bf16x8 v0 = *(const bf16x8*)(vp);
      bf16x8 v1 = *(const bf16x8*)(vp + 8);
#pragma unroll
      for (int j = 0; j < 8; ++j){
        int d = w*16 + j;
        Vt[d*64 + (((lane>>3) ^ (d&7))<<3) + (lane&7)] = v0[j];
      }
#pragma unroll
      for (int j = 0; j < 8; ++j){
        int d = w*16 + 8 + j;
        Vt[d*64 + (((lane>>3) ^ (d&7))<<3) + (lane&7)] = v1[j];
      }
    }
    __syncthreads();                            // staged data visible

    // QK^T: 4 key-tiles of 16, two D-halves each
    f32x4 s[4];
    __builtin_amdgcn_s_setprio(1);
#pragma unroll
    for (int kt = 0; kt < 4; ++kt){
      int row = kt*16 + c;
      bf16x8 k0 = *(const bf16x8*)&Ks[row*64 + ((g       ^ (row&7))<<3)];
      bf16x8 k1 = *(const bf16x8*)&Ks[row*64 + (((4 + g) ^ (row&7))<<3)];
      f32x4 z = (f32x4){0.f, 0.f, 0.f, 0.f};
      s[kt] = __builtin_amdgcn_mfma_f32_16x16x32_bf16(k0, qf0, z, 0, 0, 0);
      s[kt] = __builtin_amdgcn_mfma_f32_16x16x32_bf16(k1, qf1, s[kt], 0, 0, 0);
    }
    __builtin_amdgcn_s_setprio(0);

    // scale + causal mask + online softmax (16 scores/lane)
    float sv[16]; float cm = -1e30f;
#pragma unroll
    for (int kt = 0; kt < 4; ++kt)
#pragma unroll
      for (int r = 0; r < 4; ++r){
        int ki = c0 + kt*16 + g*4 + r;
        float val = (ki > qg) ? -1e30f : s[kt][r]*0.125f;
        sv[kt*4 + r] = val; cm = fmaxf(cm, val);
      }
    cm = fmaxf(cm, __shfl_xor(cm, 16));
    cm = fmaxf(cm, __shfl_xor(cm, 32));
    float mnew  = fmaxf(mrow, cm);
    float alpha = __expf(mrow - mnew);
    float pv[16]; float ps = 0.f;
#pragma unroll
    for (int i = 0; i < 16; ++i){ pv[i] = __expf(sv[i] - mnew); ps += pv[i]; }
    ps += __shfl_xor(ps, 16);
    ps += __shfl_xor(ps, 32);
    lrow = lrow*alpha + ps; mrow = mnew;
#pragma unroll
    for (int dt = 0; dt < 4; ++dt)
#pragma unroll
      for (int r = 0; r < 4; ++r) ot[dt][r] *= alpha;

    // P -> per-wave LDS (bf16), re-fragment for PV B-operand
    unsigned* pwp = (unsigned*)&pw[c*72 + g*4];
#pragma unroll
    for (int kt = 0; kt < 4; ++kt){
      pwp[kt*8]     = packbf(pv[kt*4+0], pv[kt*4+1]);
      pwp[kt*8 + 1] = packbf(pv[kt*4+2], pv[kt*4+3]);
    }
    asm volatile("s_waitcnt lgkmcnt(0)" ::: "memory");

    bf16x8 pb0 = *(const bf16x8*)&pw[c*72 + g*8];
    bf16x8 pb1 = *(const bf16x8*)&pw[c*72 + 32 + g*8];
    __builtin_amdgcn_s_setprio(1);
#pragma unroll
    for (int dt = 0; dt < 4; ++dt){
      int d = dt*16 + c;
      bf16x8 va0 = *(const bf16x8*)&Vt[d*64 + ((g       ^ (d&7))<<3)];
      bf16x8 va1 = *(const bf16x8*)&Vt[d*64 + (((4 + g) ^ (d&7))<<3)];
      ot[dt] = __builtin_amdgcn_mfma_f32_16x16x32_bf16(va0, pb0, ot[dt], 0, 0, 0);
      ot[dt] = __builtin_amdgcn_mfma_f32_16x16x32_bf16(va1, pb1, ot[dt], 0, 0, 0);
    }
    __builtin_amdgcn_s_setprio(0);
  }

  // epilogue: O^T frag -> out[b, q, h*64 + d], normalize; 8B packed stores
  float inv = 1.f / lrow;
  short* obase = out + (rowb + q0 + c)*HID + h*HD + g*4;
#pragma unroll
  for (int dt = 0; dt < 4; ++dt){
    unsigned u0 = packbf(ot[dt][0]*inv, ot[dt][1]*inv);
    unsigned u1 = packbf(ot[dt][2]*inv, ot[dt][3]*inv);
    uint2 uu; uu.x = u0; uu.y = u1;
    *(uint2*)(obase + dt*16) = uu;
  }
}

// ---- launch -----------------------------------------------------------
extern "C" void kernel_launch(void* const* d_in, const int* in_sizes, int n_in,
                              void* d_out, int out_size, void* d_ws, size_t ws_size,
                              hipStream_t stream){
  const float* x    = (const float*)d_in[0];
  const float* pos  = (const float*)d_in[1];
  const float* Wqkv = (const float*)d_in[2];
  const float* Wout = (const float*)d_in[3];

  short* xb     = (short*)d_ws;                 // [4096,1024] bf16(x+pos)
  short* xv     = xb    + (size_t)MROWS*HID;    // [4096,1024] bf16(x)
  short* wqkvb  = xv    + (size_t)MROWS*HID;    // [3072,1024]
  short* woutb  = wqkvb + (size_t)3*HID*HID;    // [1024,1024]
  short* qkv    = woutb + (size_t)HID*HID;      // [4096,3072]
  short* attn_o = xb;                           // reuse xb

  cast_xpos<<<dim3(MROWS*HID/1024), 256, 0, stream>>>(x, pos, xb, xv);
  cast_wmat<<<dim3(3*HID*HID/1024), 256, 0, stream>>>(Wqkv, wqkvb);
  cast_wmat<<<dim3(HID*HID/1024),   256, 0, stream>>>(Wout, woutb);

  gemm_bt<false><<<dim3(24, 32), 256, 0, stream>>>(xb, xv, 16, wqkvb, qkv, HID, 3*HID);

  attn_fwd<<<dim3(32, 32), 256, 0, stream>>>(qkv, attn_o);

  gemm_bt<true><<<dim3(8, 32), 256, 0, stream>>>(attn_o, attn_o, 8, woutb, d_out, HID, HID);
}

// Round 6
// 201.458 us; speedup vs baseline: 1.3752x; 1.2075x over previous
//
#include <hip/hip_runtime.h>
#include <hip/hip_bf16.h>
#include <stdint.h>

// Problem dims (fixed)
#define BATCH 2
#define SEQ   2048
#define HID   1024
#define NHEAD 16
#define HD    64
#define MROWS (BATCH*SEQ)   // 4096

typedef __attribute__((ext_vector_type(8))) short bf16x8;
typedef __attribute__((ext_vector_type(4))) float f32x4;

// ---- helpers ----------------------------------------------------------
__device__ inline unsigned short f2bf(float f){
  union { float f; unsigned u; } v; v.f = f;
  unsigned r = v.u + 0x7fffu + ((v.u >> 16) & 1u);   // RNE
  return (unsigned short)(r >> 16);
}
__device__ inline unsigned packbf(float a, float b){
  return (unsigned)f2bf(a) | ((unsigned)f2bf(b) << 16);
}
__device__ inline void lds_load16(const short* g, short* l){
  // async global->LDS, 16B per lane; LDS dest = wave-uniform base + lane*16
  __builtin_amdgcn_global_load_lds(
      (const __attribute__((address_space(1))) void*)g,
      (__attribute__((address_space(3))) void*)l, 16, 0, 0);
}

// ---- cast kernels (verified round-2 versions) -------------------------
__global__ __launch_bounds__(256) void cast_xpos(
    const float* __restrict__ x, const float* __restrict__ pos,
    short* __restrict__ xb, short* __restrict__ xv){
  int i = blockIdx.x * 256 + threadIdx.x;
  float4 xa = ((const float4*)x)[i];
  float4 pa = ((const float4*)pos)[i & (SEQ*HID/4 - 1)];
  short4 sb, sv;
  sb.x = (short)f2bf(xa.x + pa.x); sb.y = (short)f2bf(xa.y + pa.y);
  sb.z = (short)f2bf(xa.z + pa.z); sb.w = (short)f2bf(xa.w + pa.w);
  sv.x = (short)f2bf(xa.x); sv.y = (short)f2bf(xa.y);
  sv.z = (short)f2bf(xa.z); sv.w = (short)f2bf(xa.w);
  ((short4*)xb)[i] = sb;
  ((short4*)xv)[i] = sv;
}

__global__ __launch_bounds__(256) void cast_wmat(
    const float* __restrict__ in, short* __restrict__ out){
  int i = blockIdx.x * 256 + threadIdx.x;
  float4 a = ((const float4*)in)[i];
  short4 s;
  s.x = (short)f2bf(a.x); s.y = (short)f2bf(a.y);
  s.z = (short)f2bf(a.z); s.w = (short)f2bf(a.w);
  ((short4*)out)[i] = s;
}

// ---- GEMM: C[M,N] = A[M,K] * W[N,K]^T, bf16 inputs --------------------
// 128x128 tile, BK=32, 256 threads (4 waves, 2x2), double-buffered LDS.
// Columns bx < qsb get acc scaled by qscale (folds 1/sqrt(d) into Q).
template<bool F32OUT>
__global__ __launch_bounds__(256) void gemm_bt(
    const short* __restrict__ A0, const short* __restrict__ A1, int split_bx,
    const short* __restrict__ W, void* __restrict__ Cout, int K, int ldc,
    int qsb, float qscale){
  __shared__ alignas(16) short As[2][128*32];
  __shared__ alignas(16) short Bs[2][128*32];
  const int bx = blockIdx.x, by = blockIdx.y;
  const short* A = (bx < split_bx) ? A0 : A1;
  const int tid  = threadIdx.x;
  const int w    = tid >> 6, lane = tid & 63;
  const int g    = lane >> 4, c = lane & 15;
  const int wr   = w >> 1, wc = w & 1;

  f32x4 acc[4][4];
#pragma unroll
  for (int m = 0; m < 4; ++m)
#pragma unroll
    for (int n = 0; n < 4; ++n) acc[m][n] = (f32x4){0.f, 0.f, 0.f, 0.f};

  const short* Abase = A + (size_t)(by*128) * K;
  const short* Wbase = W + (size_t)(bx*128) * K;

  auto stage = [&](int buf, int kt){
#pragma unroll
    for (int j = 0; j < 2; ++j){
      int ci  = w*128 + j*64 + lane;
      int row = ci >> 2, sub = ci & 3;
      lds_load16(Abase + (size_t)row*K + kt + sub*8, &As[buf][(w*128 + j*64)*8]);
      lds_load16(Wbase + (size_t)row*K + kt + sub*8, &Bs[buf][(w*128 + j*64)*8]);
    }
  };

  const int nk = K >> 5;
  stage(0, 0);
  int buf = 0;
  for (int ki = 0; ki < nk; ++ki){
    __syncthreads();                       // buf staged (vm drained); prev reads done
    if (ki + 1 < nk) stage(buf ^ 1, (ki + 1) * 32);

    bf16x8 af[4], bfr[4];
#pragma unroll
    for (int m = 0; m < 4; ++m)
      af[m] = *(const bf16x8*)&As[buf][(wr*64 + m*16 + c)*32 + g*8];
#pragma unroll
    for (int n = 0; n < 4; ++n)
      bfr[n] = *(const bf16x8*)&Bs[buf][(wc*64 + n*16 + c)*32 + g*8];
    __builtin_amdgcn_s_setprio(1);
#pragma unroll
    for (int m = 0; m < 4; ++m)
#pragma unroll
      for (int n = 0; n < 4; ++n)
        acc[m][n] = __builtin_amdgcn_mfma_f32_16x16x32_bf16(af[m], bfr[n], acc[m][n], 0, 0, 0);
    __builtin_amdgcn_s_setprio(0);
    buf ^= 1;
  }

  const float sc = (bx < qsb) ? qscale : 1.0f;
  const int row0 = by*128 + wr*64;
  const int col0 = bx*128 + wc*64;
#pragma unroll
  for (int m = 0; m < 4; ++m)
#pragma unroll
    for (int n = 0; n < 4; ++n)
#pragma unroll
      for (int r = 0; r < 4; ++r){
        size_t idx = (size_t)(row0 + m*16 + g*4 + r) * ldc + (col0 + n*16 + c);
        if constexpr (F32OUT) ((float*)Cout)[idx] = acc[m][n][r] * sc;
        else                  ((short*)Cout)[idx] = (short)f2bf(acc[m][n][r] * sc);
      }
}

// ---- flash attention (causal), KVBLK=64, double-buffered K/V ----------
// 4 waves; wave w owns q-rows [qt*64 + w*16, +16). Q pre-scaled by 1/8.
// K: LDS [kv][64] with source-side XOR chunk swizzle (verified round 2).
// V: LDS [d][slot] where slot(kv) permutes keys so that a plain bf16x8
//    A-frag read (lane c,g -> row d=dt*16+c, slots 8g..8g+7 / 32+8g..)
//    delivers keys {4g+0..3, 16+4g+0..3} (+32) -- exactly P's natural
//    QK^T output order (kt, g*4+r). P never touches LDS.
//    slot(kv) = (kv>>5)*32 + ((kv>>2)&3)*8 + ((kv>>4)&1)*4 + (kv&3).
//    Same XOR chunk swizzle as K on both the scatter and the read.
// Swapped QK^T: S^T = mfma(K, Q) -> lane owns q = lane&15.
// Swapped PV:   O^T = mfma(V^T, P^T) -> q stays lane-local.
// T14 split: next chunk's V global loads issue right after the barrier,
// scatter ds_writes go after PV (land before next barrier).
__global__ __launch_bounds__(256) void attn_fwd(
    const short* __restrict__ qkv, short* __restrict__ out){
  const int bid = blockIdx.x;
  const int qt  = 31 - (bid >> 5);              // heavy blocks dispatched first
  const int bh  = bid & 31;
  const int b   = bh >> 4, h = bh & 15;
  const int tid = threadIdx.x;
  const int w   = tid >> 6, lane = tid & 63;
  const int g   = lane >> 4, c = lane & 15;

  __shared__ alignas(16) short Ks[2][64*64];    // K[kv][d], swizzled chunks
  __shared__ alignas(16) short Vt[2][64*64];    // V^T[d][slot], swizzled chunks

  const int q0 = qt*64 + w*16;
  const size_t rowb = (size_t)b * SEQ;

  const short* qptr = qkv + (rowb + q0 + c)*3072 + h*HD;
  bf16x8 qf0 = *(const bf16x8*)(qptr + g*8);
  bf16x8 qf1 = *(const bf16x8*)(qptr + 32 + g*8);

  const short* kbase = qkv + rowb*3072 + HID   + h*HD;
  const short* vbase = qkv + rowb*3072 + 2*HID + h*HD;

  // per-lane V slot permutation (lane = kv of the row this lane loads)
  const int slot   = ((lane >> 5) << 5) | (((lane >> 2) & 3) << 3)
                   | (((lane >> 4) & 1) << 2) | (lane & 3);
  const int vchunk = slot >> 3, vcol = slot & 7;

  auto stageK = [&](int buf, int c0){
#pragma unroll
    for (int j = 0; j < 2; ++j){
      int pc  = w*128 + j*64 + lane;            // physical chunk in LDS
      int row = pc >> 3;
      int lc  = (pc & 7) ^ (row & 7);           // source-side XOR swizzle
      lds_load16(kbase + (size_t)(c0 + row)*3072 + lc*8, &Ks[buf][(w*128 + j*64)*8]);
    }
  };
  auto loadV = [&](int c0, bf16x8& v0, bf16x8& v1){
    const short* vp = vbase + (size_t)(c0 + lane)*3072 + w*16;
    v0 = *(const bf16x8*)(vp);
    v1 = *(const bf16x8*)(vp + 8);
  };
  auto scatterV = [&](int buf, const bf16x8& v0, const bf16x8& v1){
#pragma unroll
    for (int j = 0; j < 8; ++j)
      Vt[buf][(w*16 + j)*64 + ((vchunk ^ (j & 7)) << 3) + vcol] = v0[j];
#pragma unroll
    for (int j = 0; j < 8; ++j)
      Vt[buf][(w*16 + 8 + j)*64 + ((vchunk ^ ((8 + j) & 7)) << 3) + vcol] = v1[j];
  };

  f32x4 ot[4];
#pragma unroll
  for (int dt = 0; dt < 4; ++dt) ot[dt] = (f32x4){0.f, 0.f, 0.f, 0.f};
  float mrow = -1e30f, lrow = 0.f;
  const int qg = q0 + c;

  // prologue: stage chunk 0
  {
    bf16x8 v0, v1;
    stageK(0, 0);
    loadV(0, v0, v1);
    scatterV(0, v0, v1);
  }
  int cur = 0;
  for (int ch = 0; ch <= qt; ++ch){
    const int c0 = ch * 64;
    __syncthreads();                            // cur staged; prev reads done

    bf16x8 nv0, nv1;
    if (ch < qt){
      stageK(cur ^ 1, c0 + 64);                 // async K prefetch
      loadV(c0 + 64, nv0, nv1);                 // V regs in flight under compute
    }

    // QK^T: 4 key-tiles of 16, two D-halves each (Q pre-scaled by 1/8)
    f32x4 s[4];
    __builtin_amdgcn_s_setprio(1);
#pragma unroll
    for (int kt = 0; kt < 4; ++kt){
      int row = kt*16 + c;
      bf16x8 k0 = *(const bf16x8*)&Ks[cur][row*64 + ((g       ^ (row&7))<<3)];
      bf16x8 k1 = *(const bf16x8*)&Ks[cur][row*64 + (((4 + g) ^ (row&7))<<3)];
      f32x4 z = (f32x4){0.f, 0.f, 0.f, 0.f};
      s[kt] = __builtin_amdgcn_mfma_f32_16x16x32_bf16(k0, qf0, z, 0, 0, 0);
      s[kt] = __builtin_amdgcn_mfma_f32_16x16x32_bf16(k1, qf1, s[kt], 0, 0, 0);
    }
    __builtin_amdgcn_s_setprio(0);

    float pv[16];
#pragma unroll
    for (int kt = 0; kt < 4; ++kt)
#pragma unroll
      for (int r = 0; r < 4; ++r) pv[kt*4 + r] = s[kt][r];

    if (ch == qt){                              // mask only the diagonal chunk
#pragma unroll
      for (int kt = 0; kt < 4; ++kt)
#pragma unroll
        for (int r = 0; r < 4; ++r){
          int ki = c0 + kt*16 + g*4 + r;
          if (ki > qg) pv[kt*4 + r] = -1e30f;
        }
    }

    // online softmax with defer-max (T13): rescale only when max grows >5.5
    float cm = fmaxf(fmaxf(fmaxf(pv[0], pv[1]), fmaxf(pv[2], pv[3])),
                     fmaxf(fmaxf(pv[4], pv[5]), fmaxf(pv[6], pv[7])));
    cm = fmaxf(cm, fmaxf(fmaxf(fmaxf(pv[8], pv[9]), fmaxf(pv[10], pv[11])),
                         fmaxf(fmaxf(pv[12], pv[13]), fmaxf(pv[14], pv[15]))));
    cm = fmaxf(cm, __shfl_xor(cm, 16));
    cm = fmaxf(cm, __shfl_xor(cm, 32));
    if (__any(cm > mrow + 5.5f)){
      float mnew  = fmaxf(mrow, cm);
      float alpha = __expf(mrow - mnew);
      lrow *= alpha;
#pragma unroll
      for (int dt = 0; dt < 4; ++dt)
#pragma unroll
        for (int r = 0; r < 4; ++r) ot[dt][r] *= alpha;
      mrow = mnew;
    }
    float ps = 0.f;
#pragma unroll
    for (int i = 0; i < 16; ++i){ pv[i] = __expf(pv[i] - mrow); ps += pv[i]; }
    ps += __shfl_xor(ps, 16);
    ps += __shfl_xor(ps, 32);
    lrow += ps;

    // pack P in-register: order (kt, g*4+r) == V slot order by construction
    union { unsigned u[4]; bf16x8 v; } pb0, pb1;
    pb0.u[0] = packbf(pv[0],  pv[1]);  pb0.u[1] = packbf(pv[2],  pv[3]);
    pb0.u[2] = packbf(pv[4],  pv[5]);  pb0.u[3] = packbf(pv[6],  pv[7]);
    pb1.u[0] = packbf(pv[8],  pv[9]);  pb1.u[1] = packbf(pv[10], pv[11]);
    pb1.u[2] = packbf(pv[12], pv[13]); pb1.u[3] = packbf(pv[14], pv[15]);

    // PV: O^T[d][q] += V^T[d][k] * P^T[k][q], plain bf16x8 frag reads
    __builtin_amdgcn_s_setprio(1);
#pragma unroll
    for (int dt = 0; dt < 4; ++dt){
      int d = dt*16 + c;
      bf16x8 va0 = *(const bf16x8*)&Vt[cur][d*64 + ((g       ^ (d&7))<<3)];
      bf16x8 va1 = *(const bf16x8*)&Vt[cur][d*64 + (((4 + g) ^ (d&7))<<3)];
      ot[dt] = __builtin_amdgcn_mfma_f32_16x16x32_bf16(va0, pb0.v, ot[dt], 0, 0, 0);
      ot[dt] = __builtin_amdgcn_mfma_f32_16x16x32_bf16(va1, pb1.v, ot[dt], 0, 0, 0);
    }
    __builtin_amdgcn_s_setprio(0);

    if (ch < qt) scatterV(cur ^ 1, nv0, nv1);   // lands before next barrier
    cur ^= 1;
  }

  // epilogue: O^T frag -> out[b, q, h*64 + d], normalize; 8B packed stores
  float inv = 1.f / lrow;
  short* obase = out + (rowb + q0 + c)*HID + h*HD + g*4;
#pragma unroll
  for (int dt = 0; dt < 4; ++dt){
    uint2 uu;
    uu.x = packbf(ot[dt][0]*inv, ot[dt][1]*inv);
    uu.y = packbf(ot[dt][2]*inv, ot[dt][3]*inv);
    *(uint2*)(obase + dt*16) = uu;
  }
}

// ---- launch -----------------------------------------------------------
extern "C" void kernel_launch(void* const* d_in, const int* in_sizes, int n_in,
                              void* d_out, int out_size, void* d_ws, size_t ws_size,
                              hipStream_t stream){
  const float* x    = (const float*)d_in[0];
  const float* pos  = (const float*)d_in[1];
  const float* Wqkv = (const float*)d_in[2];
  const float* Wout = (const float*)d_in[3];

  short* xb     = (short*)d_ws;                 // [4096,1024] bf16(x+pos)
  short* xv     = xb    + (size_t)MROWS*HID;    // [4096,1024] bf16(x)
  short* wqkvb  = xv    + (size_t)MROWS*HID;    // [3072,1024]
  short* woutb  = wqkvb + (size_t)3*HID*HID;    // [1024,1024]
  short* qkv    = woutb + (size_t)HID*HID;      // [4096,3072]
  short* attn_o = xb;                           // reuse xb

  cast_xpos<<<dim3(MROWS*HID/1024), 256, 0, stream>>>(x, pos, xb, xv);
  cast_wmat<<<dim3(3*HID*HID/1024), 256, 0, stream>>>(Wqkv, wqkvb);
  cast_wmat<<<dim3(HID*HID/1024),   256, 0, stream>>>(Wout, woutb);

  // QKV projection: cols [0,2048) use xb, cols [2048,3072) use xv.
  // Q columns (bx<8) pre-scaled by 1/sqrt(64) for attention.
  gemm_bt<false><<<dim3(24, 32), 256, 0, stream>>>(xb, xv, 16, wqkvb, qkv, HID, 3*HID,
                                                   8, 0.125f);

  attn_fwd<<<dim3(1024), 256, 0, stream>>>(qkv, attn_o);

  gemm_bt<true><<<dim3(8, 32), 256, 0, stream>>>(attn_o, attn_o, 8, woutb, d_out, HID, HID,
                                                 0, 1.0f);
}

// Round 7
// 197.095 us; speedup vs baseline: 1.4057x; 1.0221x over previous
//
#include <hip/hip_runtime.h>
#include <hip/hip_bf16.h>
#include <stdint.h>

// Problem dims (fixed)
#define BATCH 2
#define SEQ   2048
#define HID   1024
#define NHEAD 16
#define HD    64
#define MROWS (BATCH*SEQ)   // 4096

typedef __attribute__((ext_vector_type(8))) short bf16x8;
typedef __attribute__((ext_vector_type(4))) float f32x4;

// ---- helpers ----------------------------------------------------------
// native pack: bf16(a) | bf16(b)<<16 via compiler (emits v_cvt_pk_bf16_f32)
__device__ inline unsigned pk2(float a, float b){
  __hip_bfloat162 h = __float22bfloat162_rn(make_float2(a, b));
  union { __hip_bfloat162 h; unsigned u; } v; v.h = h;
  return v.u;
}
__device__ inline float fexp2(float x){
#if __has_builtin(__builtin_amdgcn_exp2f)
  return __builtin_amdgcn_exp2f(x);   // v_exp_f32 (D = 2^S0)
#else
  return exp2f(x);
#endif
}
__device__ inline void lds_load16(const short* g, short* l){
  // async global->LDS, 16B per lane; LDS dest = wave-uniform base + lane*16
  __builtin_amdgcn_global_load_lds(
      (const __attribute__((address_space(1))) void*)g,
      (__attribute__((address_space(3))) void*)l, 16, 0, 0);
}

// ---- cast kernels -----------------------------------------------------
__global__ __launch_bounds__(256) void cast_xpos(
    const float* __restrict__ x, const float* __restrict__ pos,
    short* __restrict__ xb, short* __restrict__ xv){
  int i = blockIdx.x * 256 + threadIdx.x;
  float4 xa = ((const float4*)x)[i];
  float4 pa = ((const float4*)pos)[i & (SEQ*HID/4 - 1)];
  uint2 sb, sv;
  sb.x = pk2(xa.x + pa.x, xa.y + pa.y);
  sb.y = pk2(xa.z + pa.z, xa.w + pa.w);
  sv.x = pk2(xa.x, xa.y);
  sv.y = pk2(xa.z, xa.w);
  ((uint2*)xb)[i] = sb;
  ((uint2*)xv)[i] = sv;
}

// both weight matrices in one launch (clean split at n1, no divergence)
__global__ __launch_bounds__(256) void cast_w2(
    const float* __restrict__ w1, const float* __restrict__ w2,
    short* __restrict__ o1, short* __restrict__ o2){
  int i = blockIdx.x * 256 + threadIdx.x;
  const int n1 = 3*HID*HID/4;
  const float4* src; uint2* dst; int j;
  if (i < n1){ src = (const float4*)w1; dst = (uint2*)o1; j = i; }
  else       { src = (const float4*)w2; dst = (uint2*)o2; j = i - n1; }
  float4 a = src[j];
  uint2 s;
  s.x = pk2(a.x, a.y);
  s.y = pk2(a.z, a.w);
  dst[j] = s;
}

// ---- GEMM: C[M,N] = A[M,K] * W[N,K]^T, bf16 inputs --------------------
// 128x128 tile, BK=32, 256 threads (4 waves, 2x2), double-buffered LDS.
// Columns bx < qsb get acc scaled by qscale (folds 1/sqrt(d)*log2e into Q).
template<bool F32OUT>
__global__ __launch_bounds__(256) void gemm_bt(
    const short* __restrict__ A0, const short* __restrict__ A1, int split_bx,
    const short* __restrict__ W, void* __restrict__ Cout, int K, int ldc,
    int qsb, float qscale){
  __shared__ alignas(16) short As[2][128*32];
  __shared__ alignas(16) short Bs[2][128*32];
  const int bx = blockIdx.x, by = blockIdx.y;
  const short* A = (bx < split_bx) ? A0 : A1;
  const int tid  = threadIdx.x;
  const int w    = tid >> 6, lane = tid & 63;
  const int g    = lane >> 4, c = lane & 15;
  const int wr   = w >> 1, wc = w & 1;

  f32x4 acc[4][4];
#pragma unroll
  for (int m = 0; m < 4; ++m)
#pragma unroll
    for (int n = 0; n < 4; ++n) acc[m][n] = (f32x4){0.f, 0.f, 0.f, 0.f};

  const short* Abase = A + (size_t)(by*128) * K;
  const short* Wbase = W + (size_t)(bx*128) * K;

  auto stage = [&](int buf, int kt){
#pragma unroll
    for (int j = 0; j < 2; ++j){
      int ci  = w*128 + j*64 + lane;
      int row = ci >> 2, sub = ci & 3;
      lds_load16(Abase + (size_t)row*K + kt + sub*8, &As[buf][(w*128 + j*64)*8]);
      lds_load16(Wbase + (size_t)row*K + kt + sub*8, &Bs[buf][(w*128 + j*64)*8]);
    }
  };

  const int nk = K >> 5;
  stage(0, 0);
  int buf = 0;
  for (int ki = 0; ki < nk; ++ki){
    __syncthreads();                       // buf staged (vm drained); prev reads done
    if (ki + 1 < nk) stage(buf ^ 1, (ki + 1) * 32);

    bf16x8 af[4], bfr[4];
#pragma unroll
    for (int m = 0; m < 4; ++m)
      af[m] = *(const bf16x8*)&As[buf][(wr*64 + m*16 + c)*32 + g*8];
#pragma unroll
    for (int n = 0; n < 4; ++n)
      bfr[n] = *(const bf16x8*)&Bs[buf][(wc*64 + n*16 + c)*32 + g*8];
    __builtin_amdgcn_s_setprio(1);
#pragma unroll
    for (int m = 0; m < 4; ++m)
#pragma unroll
      for (int n = 0; n < 4; ++n)
        acc[m][n] = __builtin_amdgcn_mfma_f32_16x16x32_bf16(af[m], bfr[n], acc[m][n], 0, 0, 0);
    __builtin_amdgcn_s_setprio(0);
    buf ^= 1;
  }

  const float sc = (bx < qsb) ? qscale : 1.0f;
  const int row0 = by*128 + wr*64;
  const int col0 = bx*128 + wc*64;
#pragma unroll
  for (int m = 0; m < 4; ++m)
#pragma unroll
    for (int n = 0; n < 4; ++n){
      size_t base = (size_t)(row0 + m*16 + g*4) * ldc + (col0 + n*16 + c);
      if constexpr (F32OUT){
#pragma unroll
        for (int r = 0; r < 4; ++r)
          ((float*)Cout)[base + (size_t)r*ldc] = acc[m][n][r] * sc;
      } else {
        short* p = (short*)Cout + base;
        unsigned u01 = pk2(acc[m][n][0]*sc, acc[m][n][1]*sc);
        unsigned u23 = pk2(acc[m][n][2]*sc, acc[m][n][3]*sc);
        p[0]             = (short)(u01 & 0xffff);
        p[(size_t)ldc]   = (short)(u01 >> 16);
        p[2*(size_t)ldc] = (short)(u23 & 0xffff);
        p[3*(size_t)ldc] = (short)(u23 >> 16);
      }
    }
}

// ---- flash attention (causal), KVBLK=64, double-buffered K/V ----------
// 4 waves; wave w owns q-rows [qt*64 + w*16, +16).
// Q pre-scaled by log2e/8 -> scores are in log2 units; P = exp2(s - m).
// K: LDS [kv][64] with source-side XOR chunk swizzle (verified round 2).
// V: LDS [d][slot], slot(kv) permutes keys so a plain bf16x8 A-frag read
//    delivers keys in P's natural QK^T output order (kt, g*4+r).
//    P never touches LDS. Same XOR chunk swizzle on scatter and read.
// Swapped QK^T: S^T = mfma(K, Q) -> lane owns q = lane&15.
// Swapped PV:   O^T = mfma(V^T, P^T) -> q stays lane-local.
// T14 split: next chunk's V global loads issue right after the barrier,
// scatter ds_writes go after PV (land before next barrier).
__global__ __launch_bounds__(256) void attn_fwd(
    const short* __restrict__ qkv, short* __restrict__ out){
  const int bid = blockIdx.x;
  const int qt  = 31 - (bid >> 5);              // heavy blocks dispatched first
  const int bh  = bid & 31;
  const int b   = bh >> 4, h = bh & 15;
  const int tid = threadIdx.x;
  const int w   = tid >> 6, lane = tid & 63;
  const int g   = lane >> 4, c = lane & 15;

  __shared__ alignas(16) short Ks[2][64*64];    // K[kv][d], swizzled chunks
  __shared__ alignas(16) short Vt[2][64*64];    // V^T[d][slot], swizzled chunks

  const int q0 = qt*64 + w*16;
  const size_t rowb = (size_t)b * SEQ;

  const short* qptr = qkv + (rowb + q0 + c)*3072 + h*HD;
  bf16x8 qf0 = *(const bf16x8*)(qptr + g*8);
  bf16x8 qf1 = *(const bf16x8*)(qptr + 32 + g*8);

  const short* kbase = qkv + rowb*3072 + HID   + h*HD;
  const short* vbase = qkv + rowb*3072 + 2*HID + h*HD;

  // per-lane V slot permutation (lane = kv of the row this lane loads)
  const int slot   = ((lane >> 5) << 5) | (((lane >> 2) & 3) << 3)
                   | (((lane >> 4) & 1) << 2) | (lane & 3);
  const int vchunk = slot >> 3, vcol = slot & 7;

  auto stageK = [&](int buf, int c0){
#pragma unroll
    for (int j = 0; j < 2; ++j){
      int pc  = w*128 + j*64 + lane;            // physical chunk in LDS
      int row = pc >> 3;
      int lc  = (pc & 7) ^ (row & 7);           // source-side XOR swizzle
      lds_load16(kbase + (size_t)(c0 + row)*3072 + lc*8, &Ks[buf][(w*128 + j*64)*8]);
    }
  };
  auto loadV = [&](int c0, bf16x8& v0, bf16x8& v1){
    const short* vp = vbase + (size_t)(c0 + lane)*3072 + w*16;
    v0 = *(const bf16x8*)(vp);
    v1 = *(const bf16x8*)(vp + 8);
  };
  auto scatterV = [&](int buf, const bf16x8& v0, const bf16x8& v1){
#pragma unroll
    for (int j = 0; j < 8; ++j)
      Vt[buf][(w*16 + j)*64 + ((vchunk ^ (j & 7)) << 3) + vcol] = v0[j];
#pragma unroll
    for (int j = 0; j < 8; ++j)
      Vt[buf][(w*16 + 8 + j)*64 + ((vchunk ^ ((8 + j) & 7)) << 3) + vcol] = v1[j];
  };

  f32x4 ot[4];
#pragma unroll
  for (int dt = 0; dt < 4; ++dt) ot[dt] = (f32x4){0.f, 0.f, 0.f, 0.f};
  float mrow = -1e30f, lrow = 0.f;
  const int qg = q0 + c;

  // prologue: stage chunk 0
  {
    bf16x8 v0, v1;
    stageK(0, 0);
    loadV(0, v0, v1);
    scatterV(0, v0, v1);
  }
  int cur = 0;
  for (int ch = 0; ch <= qt; ++ch){
    const int c0 = ch * 64;
    __syncthreads();                            // cur staged; prev reads done

    bf16x8 nv0, nv1;
    if (ch < qt){
      stageK(cur ^ 1, c0 + 64);                 // async K prefetch
      loadV(c0 + 64, nv0, nv1);                 // V regs in flight under compute
    }

    // QK^T: 4 key-tiles of 16, two D-halves each (scores in log2 units)
    f32x4 s[4];
    __builtin_amdgcn_s_setprio(1);
#pragma unroll
    for (int kt = 0; kt < 4; ++kt){
      int row = kt*16 + c;
      bf16x8 k0 = *(const bf16x8*)&Ks[cur][row*64 + ((g       ^ (row&7))<<3)];
      bf16x8 k1 = *(const bf16x8*)&Ks[cur][row*64 + (((4 + g) ^ (row&7))<<3)];
      f32x4 z = (f32x4){0.f, 0.f, 0.f, 0.f};
      s[kt] = __builtin_amdgcn_mfma_f32_16x16x32_bf16(k0, qf0, z, 0, 0, 0);
      s[kt] = __builtin_amdgcn_mfma_f32_16x16x32_bf16(k1, qf1, s[kt], 0, 0, 0);
    }
    __builtin_amdgcn_s_setprio(0);

    float pv[16];
#pragma unroll
    for (int kt = 0; kt < 4; ++kt)
#pragma unroll
      for (int r = 0; r < 4; ++r) pv[kt*4 + r] = s[kt][r];

    if (ch == qt){                              // mask only the diagonal chunk
#pragma unroll
      for (int kt = 0; kt < 4; ++kt)
#pragma unroll
        for (int r = 0; r < 4; ++r){
          int ki = c0 + kt*16 + g*4 + r;
          if (ki > qg) pv[kt*4 + r] = -1e30f;
        }
    }

    // online softmax (log2 domain) with defer-max: rescale when max grows >8
    float a0 = fmaxf(fmaxf(pv[0],  pv[1]),  pv[2]);
    float a1 = fmaxf(fmaxf(pv[3],  pv[4]),  pv[5]);
    float a2 = fmaxf(fmaxf(pv[6],  pv[7]),  pv[8]);
    float a3 = fmaxf(fmaxf(pv[9],  pv[10]), pv[11]);
    float a4 = fmaxf(fmaxf(pv[12], pv[13]), pv[14]);
    float cm = fmaxf(fmaxf(fmaxf(a0, a1), a2), fmaxf(fmaxf(a3, a4), pv[15]));
    cm = fmaxf(cm, __shfl_xor(cm, 16));
    cm = fmaxf(cm, __shfl_xor(cm, 32));
    if (__any(cm > mrow + 8.0f)){
      float mnew  = fmaxf(mrow, cm);
      float alpha = fexp2(mrow - mnew);
      lrow *= alpha;
#pragma unroll
      for (int dt = 0; dt < 4; ++dt)
#pragma unroll
        for (int r = 0; r < 4; ++r) ot[dt][r] *= alpha;
      mrow = mnew;
    }
    float ps = 0.f;
#pragma unroll
    for (int i = 0; i < 16; ++i){ pv[i] = fexp2(pv[i] - mrow); ps += pv[i]; }
    ps += __shfl_xor(ps, 16);
    ps += __shfl_xor(ps, 32);
    lrow += ps;

    // pack P in-register: order (kt, g*4+r) == V slot order by construction
    union { unsigned u[4]; bf16x8 v; } pb0, pb1;
    pb0.u[0] = pk2(pv[0],  pv[1]);  pb0.u[1] = pk2(pv[2],  pv[3]);
    pb0.u[2] = pk2(pv[4],  pv[5]);  pb0.u[3] = pk2(pv[6],  pv[7]);
    pb1.u[0] = pk2(pv[8],  pv[9]);  pb1.u[1] = pk2(pv[10], pv[11]);
    pb1.u[2] = pk2(pv[12], pv[13]); pb1.u[3] = pk2(pv[14], pv[15]);

    // PV: O^T[d][q] += V^T[d][k] * P^T[k][q], plain bf16x8 frag reads
    __builtin_amdgcn_s_setprio(1);
#pragma unroll
    for (int dt = 0; dt < 4; ++dt){
      int d = dt*16 + c;
      bf16x8 va0 = *(const bf16x8*)&Vt[cur][d*64 + ((g       ^ (d&7))<<3)];
      bf16x8 va1 = *(const bf16x8*)&Vt[cur][d*64 + (((4 + g) ^ (d&7))<<3)];
      ot[dt] = __builtin_amdgcn_mfma_f32_16x16x32_bf16(va0, pb0.v, ot[dt], 0, 0, 0);
      ot[dt] = __builtin_amdgcn_mfma_f32_16x16x32_bf16(va1, pb1.v, ot[dt], 0, 0, 0);
    }
    __builtin_amdgcn_s_setprio(0);

    if (ch < qt) scatterV(cur ^ 1, nv0, nv1);   // lands before next barrier
    cur ^= 1;
  }

  // epilogue: O^T frag -> out[b, q, h*64 + d], normalize; 8B packed stores
  float inv = 1.f / lrow;
  short* obase = out + (rowb + q0 + c)*HID + h*HD + g*4;
#pragma unroll
  for (int dt = 0; dt < 4; ++dt){
    uint2 uu;
    uu.x = pk2(ot[dt][0]*inv, ot[dt][1]*inv);
    uu.y = pk2(ot[dt][2]*inv, ot[dt][3]*inv);
    *(uint2*)(obase + dt*16) = uu;
  }
}

// ---- launch -----------------------------------------------------------
extern "C" void kernel_launch(void* const* d_in, const int* in_sizes, int n_in,
                              void* d_out, int out_size, void* d_ws, size_t ws_size,
                              hipStream_t stream){
  const float* x    = (const float*)d_in[0];
  const float* pos  = (const float*)d_in[1];
  const float* Wqkv = (const float*)d_in[2];
  const float* Wout = (const float*)d_in[3];

  short* xb     = (short*)d_ws;                 // [4096,1024] bf16(x+pos)
  short* xv     = xb    + (size_t)MROWS*HID;    // [4096,1024] bf16(x)
  short* wqkvb  = xv    + (size_t)MROWS*HID;    // [3072,1024]
  short* woutb  = wqkvb + (size_t)3*HID*HID;    // [1024,1024]
  short* qkv    = woutb + (size_t)HID*HID;      // [4096,3072]
  short* attn_o = xb;                           // reuse xb

  cast_xpos<<<dim3(MROWS*HID/1024), 256, 0, stream>>>(x, pos, xb, xv);
  cast_w2<<<dim3(4*HID*HID/1024), 256, 0, stream>>>(Wqkv, Wout, wqkvb, woutb);

  // QKV projection: cols [0,2048) use xb, cols [2048,3072) use xv.
  // Q columns (bx<8) pre-scaled by log2e/sqrt(64): scores in log2 units.
  gemm_bt<false><<<dim3(24, 32), 256, 0, stream>>>(xb, xv, 16, wqkvb, qkv, HID, 3*HID,
                                                   8, 0.18033688011112042f);

  attn_fwd<<<dim3(1024), 256, 0, stream>>>(qkv, attn_o);

  gemm_bt<true><<<dim3(8, 32), 256, 0, stream>>>(attn_o, attn_o, 8, woutb, d_out, HID, HID,
                                                 0, 1.0f);
}